// Round 1
// baseline (339.550 us; speedup 1.0000x reference)
//
#include <hip/hip_runtime.h>
#include <hip/hip_bf16.h>
#include <stdint.h>

// B=524288, H=64, D=1. fp32 in/out.
// R4: persistent 1024-thr blocks (grid 512, 4 chunks x 256 rows), Wc staged
// once per block; jh-grouped MFMA (acc 64->16 regs) with fused per-group
// LSTM epilogue; bf16 pack via __builtin_convertvector (HW cvt_pk, RNE);
// zero-C MFMA init with prescaled biases folded into epilogue exp2-fmas;
// cross-chunk prefetch of grad/param/mom/h0.

typedef __attribute__((ext_vector_type(8))) __bf16  bf16x8;
typedef __attribute__((ext_vector_type(8))) float   f32x8;
typedef __attribute__((ext_vector_type(4))) float   floatx4;

__device__ __forceinline__ unsigned short f2bf_bits(float x){
    unsigned u = __builtin_bit_cast(unsigned, x);
    u = u + 0x7fffu + ((u >> 16) & 1u);          // RNE
    return (unsigned short)(u >> 16);
}
__device__ __forceinline__ bf16x8 pack8(float4 a, float4 b){
    f32x8 t;
    t[0]=a.x; t[1]=a.y; t[2]=a.z; t[3]=a.w;
    t[4]=b.x; t[5]=b.y; t[6]=b.z; t[7]=b.w;
    return __builtin_convertvector(t, bf16x8);   // v_cvt_pk_bf16_f32, RNE
}

// ---------------------------------------------------------------------------
// Prep (unchanged, proven correct): Wc[256x128] bf16 in MFMA-B fragment
// order; biasc[n] = b_ih+b_hh+W_ih@b2 (raw; scaling happens at staging).
// ---------------------------------------------------------------------------
__global__ __launch_bounds__(256) void prep_kernel(
    const float* __restrict__ W2, const float* __restrict__ b2,
    const float* __restrict__ W_ih, const float* __restrict__ W_hh,
    const float* __restrict__ b_ih, const float* __restrict__ b_hh,
    unsigned short* __restrict__ wc, float* __restrict__ biasc)
{
    __shared__ float W2s[64*64];
    __shared__ float b2s[64];
    __shared__ float wihs[16*64];
    const int tid = threadIdx.x;
    const int b   = blockIdx.x;          // 0..15

    for (int i = 0; i < 4; i++){
        int idx = i*1024 + tid*4;
        *(float4*)(W2s + idx) = *(const float4*)(W2 + idx);
    }
    if (tid < 64) b2s[tid] = b2[tid];
    {
        int idx = tid*4;
        *(float4*)(wihs + idx) = *(const float4*)(W_ih + b*16*64 + idx);
    }
    __syncthreads();

    const int nl = tid >> 4;
    const int n  = b*16 + nl;
    const int jg = tid & 15;
    const int j  = jg*4;
    const int T  = n >> 4;

    float a0=0.f, a1=0.f, a2=0.f, a3=0.f;
    for (int h = 0; h < 64; h++){
        float wv = wihs[nl*64 + h];
        const float* w2r = W2s + h*64 + j;
        a0 += wv*w2r[0]; a1 += wv*w2r[1]; a2 += wv*w2r[2]; a3 += wv*w2r[3];
    }
    auto store4 = [&](int k, float v0, float v1, float v2, float v3){
        int s    = k >> 5;
        int lane = ((k >> 3) & 3)*16 + (n & 15);
        int off  = (T*4 + s)*512 + lane*8 + (k & 7);
        ushort4 v; v.x=f2bf_bits(v0); v.y=f2bf_bits(v1); v.z=f2bf_bits(v2); v.w=f2bf_bits(v3);
        *(ushort4*)(wc + off) = v;
    };
    store4(j, a0, a1, a2, a3);
    {
        const float* src = W_hh + n*64 + j;
        store4(64 + j, src[0], src[1], src[2], src[3]);
    }
    if (jg == 0){
        float s = b_ih[n] + b_hh[n];
        for (int h = 0; h < 64; h++) s += wihs[nl*64 + h]*b2s[h];
        biasc[n] = s;
    }
}

// ---------------------------------------------------------------------------
// Main: 1024 threads = 16 waves, persistent over 4 chunks x 256 rows.
// Wave w: rows [chunk_row0+16w, +16), all 256 gate cols, grouped by jh.
// ---------------------------------------------------------------------------
__global__ __launch_bounds__(1024, 4) void main_kernel(
    const float* __restrict__ grad, const float* __restrict__ param,
    const float* __restrict__ mom,  const float* __restrict__ h0,
    const float* __restrict__ c0,   const float* __restrict__ W1,
    const float* __restrict__ b1,   const float* __restrict__ Wout,
    const float* __restrict__ bout,
    const unsigned short* __restrict__ wc, const float* __restrict__ biasc,
    float* __restrict__ out)
{
    __shared__ __align__(16) unsigned short wc_l[32768];  // 64 KB
    __shared__ float  bias_l[256];   // prescaled: -log2e*b (i,f,o), +2log2e*b (g)
    __shared__ float4 w1p_l[64];     // {W1[j][0..2], b1[j]}
    __shared__ float  wout_l[64];

    const int tid  = threadIdx.x;
    const int lane = tid & 63;
    const int w    = tid >> 6;       // 0..15
    const int l15  = lane & 15;
    const int q    = lane >> 4;

    // ---- stage Wc + tables into LDS (once per block, single barrier) ----
    {
        const float4* src = (const float4*)wc;
        float4*       dst = (float4*)wc_l;
        #pragma unroll
        for (int i = 0; i < 4; i++)
            dst[i*1024 + tid] = src[i*1024 + tid];
    }
    if (tid < 256){
        float sc = ((tid >> 6) == 2) ? 2.885390082f : -1.442695041f;
        bias_l[tid] = sc * biasc[tid];
    } else if (tid < 320){
        int j = tid - 256;
        w1p_l[j] = make_float4(W1[j*3], W1[j*3+1], W1[j*3+2], b1[j]);
    } else if (tid < 384){
        wout_l[tid - 320] = Wout[tid - 320];
    }

    const float bout0 = bout[0];
    constexpr int NCH = 4;
    const long blockBase = (long)blockIdx.x * (NCH * 256);

    // ---- prologue: issue chunk-0 input loads before the barrier ----
    {
        long rA = blockBase + w*16 + l15;
        // fallthrough into loop-carried registers
        // (loads issued here overlap the LDS staging latency)
        // g_r/p_r/mo_r/ha..hd declared below.
    }
    long rA0 = blockBase + w*16 + l15;
    float g_r  = grad[rA0];
    float p_r  = param[rA0];
    float mo_r = mom[rA0];
    const float* hr0 = h0 + rA0*64;
    float4 ha = *(const float4*)(hr0 + q*8);
    float4 hb = *(const float4*)(hr0 + q*8 + 4);
    float4 hc = *(const float4*)(hr0 + 32 + q*8);
    float4 hd = *(const float4*)(hr0 + 32 + q*8 + 4);

    __syncthreads();   // wc_l / bias_l / w1p_l / wout_l ready

    const floatx4 zq = {0.f, 0.f, 0.f, 0.f};

    #pragma unroll 1
    for (int t = 0; t < NCH; ++t){
        const long rowt = blockBase + t*256;

        // ---- per-lane A-fragment build ----
        float m = fmaf(0.9f, mo_r, g_r);
        f32x8 rlo, rhi;
        #pragma unroll
        for (int jj = 0; jj < 8; jj++){
            float4 wr = w1p_l[q*8 + jj];
            float v = fmaf(wr.x, g_r, fmaf(wr.y, p_r, fmaf(wr.z, m, wr.w)));
            rlo[jj] = v > 0.f ? v : 0.f;
        }
        #pragma unroll
        for (int jj = 0; jj < 8; jj++){
            float4 wr = w1p_l[32 + q*8 + jj];
            float v = fmaf(wr.x, g_r, fmaf(wr.y, p_r, fmaf(wr.z, m, wr.w)));
            rhi[jj] = v > 0.f ? v : 0.f;
        }
        bf16x8 afr0 = __builtin_convertvector(rlo, bf16x8);
        bf16x8 afr1 = __builtin_convertvector(rhi, bf16x8);
        bf16x8 afr2 = pack8(ha, hb);
        bf16x8 afr3 = pack8(hc, hd);

        // ---- prefetch next chunk's inputs (hidden under MFMA+epilogue) ----
        if (t != NCH-1){
            long rAn = rowt + 256 + w*16 + l15;
            g_r  = grad[rAn];
            p_r  = param[rAn];
            mo_r = mom[rAn];
            const float* hrn = h0 + rAn*64;
            ha = *(const float4*)(hrn + q*8);
            hb = *(const float4*)(hrn + q*8 + 4);
            hc = *(const float4*)(hrn + 32 + q*8);
            hd = *(const float4*)(hrn + 32 + q*8 + 4);
        }

        const float* c0b = c0 + (rowt + w*16 + q*4)*64 + l15;
        float red[4] = {0.f, 0.f, 0.f, 0.f};

        // ---- 4 column-groups: 16 MFMAs each, epilogue fused per group ----
        #pragma unroll 1
        for (int jh = 0; jh < 4; ++jh){
            const int jh16 = jh << 4;

            // c0 for this lane's 4 rows at col jh16+l15 (issued first; the
            // 16 ds_reads + 16 MFMAs below cover the latency)
            float c0v[4];
            c0v[0] = c0b[jh16];
            c0v[1] = c0b[jh16 + 64];
            c0v[2] = c0b[jh16 + 128];
            c0v[3] = c0b[jh16 + 192];

            float bsi = bias_l[jh16 + l15];
            float bsf = bias_l[jh16 + l15 + 64];
            float bsg = bias_l[jh16 + l15 + 128];
            float bso = bias_l[jh16 + l15 + 192];
            float wo  = wout_l[jh16 + l15];

            const unsigned short* cb = wc_l + jh*2048 + lane*8;
            #define BFRAG(o) (*(const bf16x8*)(cb + (o)))
            floatx4 xi, xf, xg, xo;
            xi = __builtin_amdgcn_mfma_f32_16x16x32_bf16(afr0, BFRAG(0),         zq, 0,0,0);
            xi = __builtin_amdgcn_mfma_f32_16x16x32_bf16(afr1, BFRAG(512),       xi, 0,0,0);
            xi = __builtin_amdgcn_mfma_f32_16x16x32_bf16(afr2, BFRAG(1024),      xi, 0,0,0);
            xi = __builtin_amdgcn_mfma_f32_16x16x32_bf16(afr3, BFRAG(1536),      xi, 0,0,0);
            xf = __builtin_amdgcn_mfma_f32_16x16x32_bf16(afr0, BFRAG(8192),      zq, 0,0,0);
            xf = __builtin_amdgcn_mfma_f32_16x16x32_bf16(afr1, BFRAG(8192+512),  xf, 0,0,0);
            xf = __builtin_amdgcn_mfma_f32_16x16x32_bf16(afr2, BFRAG(8192+1024), xf, 0,0,0);
            xf = __builtin_amdgcn_mfma_f32_16x16x32_bf16(afr3, BFRAG(8192+1536), xf, 0,0,0);
            xg = __builtin_amdgcn_mfma_f32_16x16x32_bf16(afr0, BFRAG(16384),     zq, 0,0,0);
            xg = __builtin_amdgcn_mfma_f32_16x16x32_bf16(afr1, BFRAG(16384+512), xg, 0,0,0);
            xg = __builtin_amdgcn_mfma_f32_16x16x32_bf16(afr2, BFRAG(16384+1024),xg, 0,0,0);
            xg = __builtin_amdgcn_mfma_f32_16x16x32_bf16(afr3, BFRAG(16384+1536),xg, 0,0,0);
            xo = __builtin_amdgcn_mfma_f32_16x16x32_bf16(afr0, BFRAG(24576),     zq, 0,0,0);
            xo = __builtin_amdgcn_mfma_f32_16x16x32_bf16(afr1, BFRAG(24576+512), xo, 0,0,0);
            xo = __builtin_amdgcn_mfma_f32_16x16x32_bf16(afr2, BFRAG(24576+1024),xo, 0,0,0);
            xo = __builtin_amdgcn_mfma_f32_16x16x32_bf16(afr3, BFRAG(24576+1536),xo, 0,0,0);
            #undef BFRAG

            // LSTM epilogue slice (bias folded into the exp2 fma via bs*)
            #pragma unroll
            for (int r = 0; r < 4; ++r){
                float ei = __builtin_amdgcn_exp2f(fmaf(-1.442695041f, xi[r], bsi));
                float iv = __builtin_amdgcn_rcpf(1.0f + ei);
                float ef = __builtin_amdgcn_exp2f(fmaf(-1.442695041f, xf[r], bsf));
                float fv = __builtin_amdgcn_rcpf(1.0f + ef);
                float eo = __builtin_amdgcn_exp2f(fmaf(-1.442695041f, xo[r], bso));
                float ov = __builtin_amdgcn_rcpf(1.0f + eo);
                float eg = __builtin_amdgcn_exp2f(fmaf( 2.885390082f, xg[r], bsg));
                float gv = fmaf(-2.0f, __builtin_amdgcn_rcpf(1.0f + eg), 1.0f);
                float c1 = fmaf(fv, c0v[r], iv*gv);
                float ec = __builtin_amdgcn_exp2f(2.885390082f * c1);
                float tv = fmaf(-2.0f, __builtin_amdgcn_rcpf(1.0f + ec), 1.0f);
                float h1 = ov * tv;
                red[r] = fmaf(h1, wo, red[r]);
            }
        }

        // ---- reduce over l15 (16-lane butterfly), store ----
        #pragma unroll
        for (int mset = 1; mset < 16; mset <<= 1)
            #pragma unroll
            for (int r = 0; r < 4; r++)
                red[r] += __shfl_xor(red[r], mset, 64);

        if (l15 == 0){
            long orow = rowt + w*16 + q*4;
            #pragma unroll
            for (int r = 0; r < 4; r++)
                out[orow + r] = red[r] + bout0;
        }
    }
}

extern "C" void kernel_launch(void* const* d_in, const int* in_sizes, int n_in,
                              void* d_out, int out_size, void* d_ws, size_t ws_size,
                              hipStream_t stream)
{
    const float* grad  = (const float*)d_in[0];
    const float* param = (const float*)d_in[1];
    const float* mom   = (const float*)d_in[2];
    const float* h0    = (const float*)d_in[3];
    const float* c0    = (const float*)d_in[4];
    const float* W1    = (const float*)d_in[5];
    const float* b1    = (const float*)d_in[6];
    const float* W2    = (const float*)d_in[7];
    const float* b2    = (const float*)d_in[8];
    const float* W_ih  = (const float*)d_in[9];
    const float* W_hh  = (const float*)d_in[10];
    const float* b_ih  = (const float*)d_in[11];
    const float* b_hh  = (const float*)d_in[12];
    const float* Wout  = (const float*)d_in[13];
    const float* bout  = (const float*)d_in[14];

    unsigned short* wc = (unsigned short*)d_ws;
    float* biasc       = (float*)((char*)d_ws + 65536);

    prep_kernel<<<16, 256, 0, stream>>>(W2, b2, W_ih, W_hh, b_ih, b_hh, wc, biasc);

    const int nblocks = 524288 / (4 * 256);   // 512 persistent blocks
    main_kernel<<<nblocks, 1024, 0, stream>>>(grad, param, mom, h0, c0,
                                              W1, b1, Wout, bout, wc, biasc,
                                              (float*)d_out);
}

// Round 2
// 314.114 us; speedup vs baseline: 1.0810x; 1.0810x over previous
//
#include <hip/hip_runtime.h>
#include <hip/hip_bf16.h>
#include <stdint.h>

// B=524288, H=64, D=1. fp32 in/out.
// R5: R3 structure (512-thr blocks, one-shot, Wc staged per block) with:
//  - 32 rows per wave (two 16-row sets) sharing every B-fragment ds_read
//    -> LDS-port pressure halved (the dominant pipe per the R3 arithmetic)
//  - jh-outer / gate-inner loop: B live = 4 frags (16 regs), acc = 32 regs,
//    A-frags = 32 regs  => ~105 VGPR static peak, under the (512,4) 128 cap
//  - HW cvt_pk bf16 packing (__builtin_convertvector, RNE)
//  - zero-C MFMA init, biases prescaled by -log2e / +2log2e and folded into
//    the epilogue exp2 fmas (no C-broadcast movs, no separate bias add)

typedef __attribute__((ext_vector_type(8))) __bf16  bf16x8;
typedef __attribute__((ext_vector_type(8))) float   f32x8;
typedef __attribute__((ext_vector_type(4))) float   floatx4;

__device__ __forceinline__ unsigned short f2bf_bits(float x){
    unsigned u = __builtin_bit_cast(unsigned, x);
    u = u + 0x7fffu + ((u >> 16) & 1u);          // RNE
    return (unsigned short)(u >> 16);
}
__device__ __forceinline__ bf16x8 pack8(float4 a, float4 b){
    f32x8 t;
    t[0]=a.x; t[1]=a.y; t[2]=a.z; t[3]=a.w;
    t[4]=b.x; t[5]=b.y; t[6]=b.z; t[7]=b.w;
    return __builtin_convertvector(t, bf16x8);   // v_cvt_pk_bf16_f32, RNE
}

// ---------------------------------------------------------------------------
// Prep (unchanged, proven correct): Wc[256x128] bf16 in MFMA-B fragment
// order; biasc[n] = b_ih+b_hh+W_ih@b2 (raw; prescaling happens at staging).
// ---------------------------------------------------------------------------
__global__ __launch_bounds__(256) void prep_kernel(
    const float* __restrict__ W2, const float* __restrict__ b2,
    const float* __restrict__ W_ih, const float* __restrict__ W_hh,
    const float* __restrict__ b_ih, const float* __restrict__ b_hh,
    unsigned short* __restrict__ wc, float* __restrict__ biasc)
{
    __shared__ float W2s[64*64];
    __shared__ float b2s[64];
    __shared__ float wihs[16*64];
    const int tid = threadIdx.x;
    const int b   = blockIdx.x;          // 0..15

    for (int i = 0; i < 4; i++){
        int idx = i*1024 + tid*4;
        *(float4*)(W2s + idx) = *(const float4*)(W2 + idx);
    }
    if (tid < 64) b2s[tid] = b2[tid];
    {
        int idx = tid*4;
        *(float4*)(wihs + idx) = *(const float4*)(W_ih + b*16*64 + idx);
    }
    __syncthreads();

    const int nl = tid >> 4;
    const int n  = b*16 + nl;
    const int jg = tid & 15;
    const int j  = jg*4;
    const int T  = n >> 4;

    float a0=0.f, a1=0.f, a2=0.f, a3=0.f;
    for (int h = 0; h < 64; h++){
        float wv = wihs[nl*64 + h];
        const float* w2r = W2s + h*64 + j;
        a0 += wv*w2r[0]; a1 += wv*w2r[1]; a2 += wv*w2r[2]; a3 += wv*w2r[3];
    }
    auto store4 = [&](int k, float v0, float v1, float v2, float v3){
        int s    = k >> 5;
        int lane = ((k >> 3) & 3)*16 + (n & 15);
        int off  = (T*4 + s)*512 + lane*8 + (k & 7);
        ushort4 v; v.x=f2bf_bits(v0); v.y=f2bf_bits(v1); v.z=f2bf_bits(v2); v.w=f2bf_bits(v3);
        *(ushort4*)(wc + off) = v;
    };
    store4(j, a0, a1, a2, a3);
    {
        const float* src = W_hh + n*64 + j;
        store4(64 + j, src[0], src[1], src[2], src[3]);
    }
    if (jg == 0){
        float s = b_ih[n] + b_hh[n];
        for (int h = 0; h < 64; h++) s += wihs[nl*64 + h]*b2s[h];
        biasc[n] = s;
    }
}

// ---------------------------------------------------------------------------
// Main: 512 threads = 8 waves, 256 rows/block, 2048 blocks.
// Wave w: rows [row0+32w, row0+32w+32) as two 16-row sets sharing B-reads.
// ---------------------------------------------------------------------------
__global__ __launch_bounds__(512, 4) void main_kernel(
    const float* __restrict__ grad, const float* __restrict__ param,
    const float* __restrict__ mom,  const float* __restrict__ h0,
    const float* __restrict__ c0,   const float* __restrict__ W1,
    const float* __restrict__ b1,   const float* __restrict__ Wout,
    const float* __restrict__ bout,
    const unsigned short* __restrict__ wc, const float* __restrict__ biasc,
    float* __restrict__ out)
{
    __shared__ __align__(16) unsigned short wc_l[32768];  // 64 KB
    __shared__ float  bias_l[256];   // prescaled: -log2e*b (i,f,o), +2log2e*b (g)
    __shared__ float4 w1p_l[64];     // {W1[j][0..2], b1[j]}
    __shared__ float  wout_l[64];

    const int tid  = threadIdx.x;
    const int lane = tid & 63;
    const int w    = tid >> 6;       // 0..7
    const int l15  = lane & 15;
    const int q    = lane >> 4;
    const long row0 = (long)blockIdx.x * 256;

    // ---- stage Wc + tables into LDS (single barrier) ----
    {
        const float4* src = (const float4*)wc;
        float4*       dst = (float4*)wc_l;
        #pragma unroll
        for (int i = 0; i < 8; i++)
            dst[i*512 + tid] = src[i*512 + tid];
    }
    if (tid < 256){
        float sc = ((tid >> 6) == 2) ? 2.885390082f : -1.442695041f;
        bias_l[tid] = sc * biasc[tid];
    } else if (tid < 320){
        int j = tid - 256;
        w1p_l[j] = make_float4(W1[j*3], W1[j*3+1], W1[j*3+2], b1[j]);
    } else if (tid < 384){
        wout_l[tid - 320] = Wout[tid - 320];
    }

    // ---- per-lane input loads for BOTH sets (issued under staging) ----
    const long rA0 = row0 + w*32 + l15;      // set 0
    const long rA1 = rA0 + 16;               // set 1
    float g0 = grad[rA0], p0 = param[rA0], mo0 = mom[rA0];
    float g1 = grad[rA1], p1 = param[rA1], mo1 = mom[rA1];
    const float* hr0 = h0 + rA0*64;
    float4 ha0 = *(const float4*)(hr0 + q*8);
    float4 hb0 = *(const float4*)(hr0 + q*8 + 4);
    float4 hc0 = *(const float4*)(hr0 + 32 + q*8);
    float4 hd0 = *(const float4*)(hr0 + 32 + q*8 + 4);
    const float* hr1 = h0 + rA1*64;
    float4 ha1 = *(const float4*)(hr1 + q*8);
    float4 hb1 = *(const float4*)(hr1 + q*8 + 4);
    float4 hc1 = *(const float4*)(hr1 + 32 + q*8);
    float4 hd1 = *(const float4*)(hr1 + 32 + q*8 + 4);
    const float bout0 = bout[0];

    __syncthreads();   // wc_l / bias_l / w1p_l / wout_l ready

    // ---- A-fragment build, both sets ----
    float m0 = fmaf(0.9f, mo0, g0);
    float m1 = fmaf(0.9f, mo1, g1);
    f32x8 rlo0, rhi0, rlo1, rhi1;
    #pragma unroll
    for (int jj = 0; jj < 8; jj++){
        float4 wr = w1p_l[q*8 + jj];
        float v0 = fmaf(wr.x, g0, fmaf(wr.y, p0, fmaf(wr.z, m0, wr.w)));
        float v1 = fmaf(wr.x, g1, fmaf(wr.y, p1, fmaf(wr.z, m1, wr.w)));
        rlo0[jj] = v0 > 0.f ? v0 : 0.f;
        rlo1[jj] = v1 > 0.f ? v1 : 0.f;
    }
    #pragma unroll
    for (int jj = 0; jj < 8; jj++){
        float4 wr = w1p_l[32 + q*8 + jj];
        float v0 = fmaf(wr.x, g0, fmaf(wr.y, p0, fmaf(wr.z, m0, wr.w)));
        float v1 = fmaf(wr.x, g1, fmaf(wr.y, p1, fmaf(wr.z, m1, wr.w)));
        rhi0[jj] = v0 > 0.f ? v0 : 0.f;
        rhi1[jj] = v1 > 0.f ? v1 : 0.f;
    }
    bf16x8 a0_0 = __builtin_convertvector(rlo0, bf16x8);
    bf16x8 a1_0 = __builtin_convertvector(rhi0, bf16x8);
    bf16x8 a2_0 = pack8(ha0, hb0);
    bf16x8 a3_0 = pack8(hc0, hd0);
    bf16x8 a0_1 = __builtin_convertvector(rlo1, bf16x8);
    bf16x8 a1_1 = __builtin_convertvector(rhi1, bf16x8);
    bf16x8 a2_1 = pack8(ha1, hb1);
    bf16x8 a3_1 = pack8(hc1, hd1);

    const float* c0b0 = c0 + (row0 + w*32 + q*4)*64 + l15;        // set 0
    const float* c0b1 = c0 + (row0 + w*32 + 16 + q*4)*64 + l15;   // set 1

    float red0[4] = {0.f, 0.f, 0.f, 0.f};
    float red1[4] = {0.f, 0.f, 0.f, 0.f};
    const floatx4 zq = {0.f, 0.f, 0.f, 0.f};

    // ---- 4 column-groups; gates i,f,g,o inner; B-frags shared by both sets
    #pragma unroll 1
    for (int jh = 0; jh < 4; ++jh){
        const int jh16 = jh << 4;

        // c0 for this lane's rows at col jh16+l15 (issued first; covered by
        // the 16 ds_reads + 32 MFMAs below)
        float c00[4], c01[4];
        #pragma unroll
        for (int r = 0; r < 4; ++r){
            c00[r] = c0b0[jh16 + r*64];
            c01[r] = c0b1[jh16 + r*64];
        }

        float bsi = bias_l[jh16 + l15];
        float bsf = bias_l[jh16 + l15 + 64];
        float bsg = bias_l[jh16 + l15 + 128];
        float bso = bias_l[jh16 + l15 + 192];
        float wo  = wout_l[jh16 + l15];

        const unsigned short* cb = wc_l + jh*2048 + lane*8;
        floatx4 xi0, xi1, xf0, xf1, xg0, xg1, xo0, xo1;

        #define GATE(Gofs, d0, d1)                                            \
        {                                                                     \
            bf16x8 t0 = *(const bf16x8*)(cb + (Gofs));                        \
            bf16x8 t1 = *(const bf16x8*)(cb + (Gofs) + 512);                  \
            bf16x8 t2 = *(const bf16x8*)(cb + (Gofs) + 1024);                 \
            bf16x8 t3 = *(const bf16x8*)(cb + (Gofs) + 1536);                 \
            d0 = __builtin_amdgcn_mfma_f32_16x16x32_bf16(a0_0, t0, zq, 0,0,0);\
            d1 = __builtin_amdgcn_mfma_f32_16x16x32_bf16(a0_1, t0, zq, 0,0,0);\
            d0 = __builtin_amdgcn_mfma_f32_16x16x32_bf16(a1_0, t1, d0, 0,0,0);\
            d1 = __builtin_amdgcn_mfma_f32_16x16x32_bf16(a1_1, t1, d1, 0,0,0);\
            d0 = __builtin_amdgcn_mfma_f32_16x16x32_bf16(a2_0, t2, d0, 0,0,0);\
            d1 = __builtin_amdgcn_mfma_f32_16x16x32_bf16(a2_1, t2, d1, 0,0,0);\
            d0 = __builtin_amdgcn_mfma_f32_16x16x32_bf16(a3_0, t3, d0, 0,0,0);\
            d1 = __builtin_amdgcn_mfma_f32_16x16x32_bf16(a3_1, t3, d1, 0,0,0);\
        }
        GATE(0,     xi0, xi1)      // gate i  (tiles 0..3)
        GATE(8192,  xf0, xf1)      // gate f  (tiles 4..7)
        GATE(16384, xg0, xg1)      // gate g  (tiles 8..11)
        GATE(24576, xo0, xo1)      // gate o  (tiles 12..15)
        #undef GATE

        // LSTM epilogue, both sets (bias folded into exp2 fmas)
        #pragma unroll
        for (int r = 0; r < 4; ++r){
            float ei = __builtin_amdgcn_exp2f(fmaf(-1.442695041f, xi0[r], bsi));
            float iv = __builtin_amdgcn_rcpf(1.0f + ei);
            float ef = __builtin_amdgcn_exp2f(fmaf(-1.442695041f, xf0[r], bsf));
            float fv = __builtin_amdgcn_rcpf(1.0f + ef);
            float eo = __builtin_amdgcn_exp2f(fmaf(-1.442695041f, xo0[r], bso));
            float ov = __builtin_amdgcn_rcpf(1.0f + eo);
            float eg = __builtin_amdgcn_exp2f(fmaf( 2.885390082f, xg0[r], bsg));
            float gv = fmaf(-2.0f, __builtin_amdgcn_rcpf(1.0f + eg), 1.0f);
            float c1 = fmaf(fv, c00[r], iv*gv);
            float ec = __builtin_amdgcn_exp2f(2.885390082f * c1);
            float tv = fmaf(-2.0f, __builtin_amdgcn_rcpf(1.0f + ec), 1.0f);
            red0[r] = fmaf(ov * tv, wo, red0[r]);
        }
        #pragma unroll
        for (int r = 0; r < 4; ++r){
            float ei = __builtin_amdgcn_exp2f(fmaf(-1.442695041f, xi1[r], bsi));
            float iv = __builtin_amdgcn_rcpf(1.0f + ei);
            float ef = __builtin_amdgcn_exp2f(fmaf(-1.442695041f, xf1[r], bsf));
            float fv = __builtin_amdgcn_rcpf(1.0f + ef);
            float eo = __builtin_amdgcn_exp2f(fmaf(-1.442695041f, xo1[r], bso));
            float ov = __builtin_amdgcn_rcpf(1.0f + eo);
            float eg = __builtin_amdgcn_exp2f(fmaf( 2.885390082f, xg1[r], bsg));
            float gv = fmaf(-2.0f, __builtin_amdgcn_rcpf(1.0f + eg), 1.0f);
            float c1 = fmaf(fv, c01[r], iv*gv);
            float ec = __builtin_amdgcn_exp2f(2.885390082f * c1);
            float tv = fmaf(-2.0f, __builtin_amdgcn_rcpf(1.0f + ec), 1.0f);
            red1[r] = fmaf(ov * tv, wo, red1[r]);
        }
    }

    // ---- reduce over l15 (16-lane butterfly), store both sets ----
    #pragma unroll
    for (int mset = 1; mset < 16; mset <<= 1)
        #pragma unroll
        for (int r = 0; r < 4; r++){
            red0[r] += __shfl_xor(red0[r], mset, 64);
            red1[r] += __shfl_xor(red1[r], mset, 64);
        }

    if (l15 == 0){
        long orow0 = row0 + w*32 + q*4;
        #pragma unroll
        for (int r = 0; r < 4; r++){
            out[orow0 + r]      = red0[r] + bout0;
            out[orow0 + 16 + r] = red1[r] + bout0;
        }
    }
}

extern "C" void kernel_launch(void* const* d_in, const int* in_sizes, int n_in,
                              void* d_out, int out_size, void* d_ws, size_t ws_size,
                              hipStream_t stream)
{
    const float* grad  = (const float*)d_in[0];
    const float* param = (const float*)d_in[1];
    const float* mom   = (const float*)d_in[2];
    const float* h0    = (const float*)d_in[3];
    const float* c0    = (const float*)d_in[4];
    const float* W1    = (const float*)d_in[5];
    const float* b1    = (const float*)d_in[6];
    const float* W2    = (const float*)d_in[7];
    const float* b2    = (const float*)d_in[8];
    const float* W_ih  = (const float*)d_in[9];
    const float* W_hh  = (const float*)d_in[10];
    const float* b_ih  = (const float*)d_in[11];
    const float* b_hh  = (const float*)d_in[12];
    const float* Wout  = (const float*)d_in[13];
    const float* bout  = (const float*)d_in[14];

    unsigned short* wc = (unsigned short*)d_ws;
    float* biasc       = (float*)((char*)d_ws + 65536);

    prep_kernel<<<16, 256, 0, stream>>>(W2, b2, W_ih, W_hh, b_ih, b_hh, wc, biasc);

    const int nblocks = 524288 / 256;   // 2048
    main_kernel<<<nblocks, 512, 0, stream>>>(grad, param, mom, h0, c0,
                                             W1, b1, Wout, bout, wc, biasc,
                                             (float*)d_out);
}